// Round 23
// baseline (125.977 us; speedup 1.0000x reference)
//
#include <hip/hip_runtime.h>
#include <math.h>

#define SEQ 130
#define EMB 16
#define LIN 1039
#define NB 2          // batches per wave
#define WPB 4         // waves per block (256 threads)
#define LOG2E 1.4426950408889634f

typedef __attribute__((ext_vector_type(4))) _Float16 half4v;
typedef __attribute__((ext_vector_type(4))) float float4v;

// pe2[s][e] = posenc(s,e) + b_proj[e] for s<SEQ; 0 for s in [SEQ,144)
__global__ void pe_kernel(const float* __restrict__ b_proj, float* __restrict__ pe2) {
    int idx = blockIdx.x * 256 + threadIdx.x;   // s*16+e
    if (idx < 144 * 16) {
        int s = idx >> 4, e = idx & 15;
        float v = 0.f;
        if (s < SEQ) {
            int i = e >> 1;
            float div = expf(-(float)(2 * i) * 0.57564627324851149f); // ln(1e4)/16
            float ang = (float)s * div;
            v = ((e & 1) ? cosf(ang) : sinf(ang)) + b_proj[e];
        }
        pe2[idx] = v;
    }
}

// One wave = one batch end-to-end. No LDS, no barriers, no-max softmax.
// Phase 3: paired q-tiles + dual PV accumulators (R19/R20-proven, 124 VGPR).
// exp2-folded softmax (wk,bk pre-scaled by log2e; v_exp_f32 IS 2^x on gfx950).
// Posenc folded into phase-1 MFMA C operand.
// frag(c,g,j)=M[c][4g+j]; D=mfma(M1,M2,C) => D[c][f]=sum_k M1[f][k]*M2[c][k]+C[c][f]
// NOTE: no min-waves hint (R10/R13 spill storms). VGPR must stay <=128
// (R19: 128 -> 4 waves/SIMD, 20.5% occ; R21/R22: 144/164 -> 11% occ, regress).
__global__ __launch_bounds__(256) void st_kernel(
    const float* __restrict__ x,
    const float* __restrict__ w_proj,
    const float* __restrict__ w_in,  const float* __restrict__ b_in,
    const float* __restrict__ w_out, const float* __restrict__ b_out,
    const float* __restrict__ ln1_g, const float* __restrict__ ln1_b,
    const float* __restrict__ w1,    const float* __restrict__ b1,
    const float* __restrict__ w2,    const float* __restrict__ b2,
    const float* __restrict__ ln2_g, const float* __restrict__ ln2_b,
    const float* __restrict__ pe2,
    int nbat,
    float* __restrict__ out)
{
    const int tid  = threadIdx.x;
    const int lane = tid & 63;
    const int c    = lane & 15;
    const int g    = lane >> 4;
    const int wgid = blockIdx.x * WPB + (tid >> 6);
    const float4v zero4 = {0.f, 0.f, 0.f, 0.f};

    // ---- per-lane weight fragments (wk scaled by log2e for exp2 softmax) ----
    half4v wprojF, wqF, wkF, wvF, woF;
    {
        #pragma unroll
        for (int j = 0; j < 4; ++j)
            wprojF[j] = (_Float16)((g < 2) ? w_proj[c * 8 + 4 * g + j] : 0.f);
        const float* pq = &w_in[c * 16 + 4 * g];
        const float* pk = &w_in[(16 + c) * 16 + 4 * g];
        const float* pv = &w_in[(32 + c) * 16 + 4 * g];
        const float* po = &w_out[c * 16 + 4 * g];
        #pragma unroll
        for (int j = 0; j < 4; ++j) {
            wqF[j] = (_Float16)(pq[j] * 0.25f);
            wkF[j] = (_Float16)(pk[j] * LOG2E);
            wvF[j] = (_Float16)pv[j];
            woF[j] = (_Float16)po[j];
        }
    }
    // ---- packed f16 per-lane params ----
    half4v bqH, bkH, boH, g1H, b1H, g2H, b2H, w1H, w2H, bb2H;
    #pragma unroll
    for (int j = 0; j < 4; ++j) {
        const int f = 4 * g + j;
        bqH[j]  = (_Float16)(b_in[f] * 0.25f);
        bkH[j]  = (_Float16)(b_in[16 + f] * LOG2E);
        boH[j]  = (_Float16)b_out[f];
        g1H[j]  = (_Float16)ln1_g[f];  b1H[j]  = (_Float16)ln1_b[f];
        g2H[j]  = (_Float16)ln2_g[f];  b2H[j]  = (_Float16)ln2_b[f];
        w1H[j]  = (_Float16)w1[f];     w2H[j]  = (_Float16)w2[f];
        bb2H[j] = (_Float16)b2[f];
    }
    const float bvc = b_in[32 + c];
    const float b1v = b1[0];

    for (int bi = 0; bi < NB; ++bi) {
        const int batch = wgid * NB + bi;
        if (batch >= nbat) break;
        const float* xrow = x + (size_t)batch * LIN;

        // ---- phase 1: h = mfma(wproj, x, posenc) (K padded 8->16) ----
        half4v hf[9];
        #pragma unroll
        for (int st = 0; st < 9; ++st) {
            const int s = st * 16 + c;
            half4v xf;
            if (st < 8) {
                if (g < 2) {
                    const float* xp = &xrow[s * 8 + 4 * g];
                    #pragma unroll
                    for (int j = 0; j < 4; ++j) xf[j] = (_Float16)xp[j];
                } else {
                    #pragma unroll
                    for (int j = 0; j < 4; ++j) xf[j] = (_Float16)0.f;
                }
            } else {
                #pragma unroll
                for (int j = 0; j < 4; ++j) {
                    const int idx = s * 8 + 4 * g + j;
                    const float v = (g < 2 && idx < LIN) ? xrow[idx] : 0.f;
                    xf[j] = (_Float16)v;
                }
            }
            const float4v pe4 = *(const float4v*)&pe2[s * 16 + 4 * g];
            float4v d = __builtin_amdgcn_mfma_f32_16x16x16f16(wprojF, xf, pe4, 0, 0, 0);
            #pragma unroll
            for (int j = 0; j < 4; ++j) hf[st][j] = (_Float16)d[j];
        }

        // ---- phase 2: k (log2e-scaled, in-lane), V^T (operand swap) ----
        half4v kf[9], vf[9];
        #pragma unroll
        for (int st = 0; st < 9; ++st) {
            float4v dk = __builtin_amdgcn_mfma_f32_16x16x16f16(wkF, hf[st], zero4, 0, 0, 0);
            float4v dv = __builtin_amdgcn_mfma_f32_16x16x16f16(hf[st], wvF, zero4, 0, 0, 0);
            #pragma unroll
            for (int j = 0; j < 4; ++j) {
                kf[st][j] = (_Float16)(dk[j] + (float)bkH[j]);
                vf[st][j] = (_Float16)(dv[j] + bvc);
            }
        }

        // ---- phase 3: paired tiles — 2 independent chains everywhere ----
        float accm[4] = {0.f, 0.f, 0.f, 0.f};
        #pragma unroll
        for (int p = 0; p < 5; ++p) {
            const int nt = (p < 4) ? 2 : 1;     // pair (0..3), tile 8 alone
            half4v qf[2];
            float4v Oa[2], Ob[2];
            float l[2];
            #pragma unroll
            for (int u = 0; u < 2; ++u) if (u < nt) {
                const int ti = 2 * p + u;
                float4v dq = __builtin_amdgcn_mfma_f32_16x16x16f16(wqF, hf[ti], zero4, 0, 0, 0);
                #pragma unroll
                for (int j = 0; j < 4; ++j) qf[u][j] = (_Float16)(dq[j] + (float)bqH[j]);
                Oa[u] = zero4; Ob[u] = zero4; l[u] = 0.f;
            }
            #pragma unroll
            for (int kt = 0; kt < 9; ++kt) {
                #pragma unroll
                for (int u = 0; u < 2; ++u) if (u < nt) {
                    float4v s4 = __builtin_amdgcn_mfma_f32_16x16x16f16(kf[kt], qf[u], zero4, 0, 0, 0);
                    float p0 = exp2f(s4[0]), p1 = exp2f(s4[1]);
                    float p2 = exp2f(s4[2]), p3 = exp2f(s4[3]);
                    if (kt == 8) {      // k-rows 128+4g+j valid only when 4g+j<2
                        p2 = 0.f; p3 = 0.f;
                        if (g > 0) { p0 = 0.f; p1 = 0.f; }
                    }
                    l[u] += (p0 + p1) + (p2 + p3);
                    half4v pf = {(_Float16)p0, (_Float16)p1, (_Float16)p2, (_Float16)p3};
                    if (kt & 1) Ob[u] = __builtin_amdgcn_mfma_f32_16x16x16f16(vf[kt], pf, Ob[u], 0, 0, 0);
                    else        Oa[u] = __builtin_amdgcn_mfma_f32_16x16x16f16(vf[kt], pf, Oa[u], 0, 0, 0);
                }
            }
            #pragma unroll
            for (int u = 0; u < 2; ++u) if (u < nt) l[u] += __shfl_xor(l[u], 16);
            #pragma unroll
            for (int u = 0; u < 2; ++u) if (u < nt) l[u] += __shfl_xor(l[u], 32);
            // two independent epilogues (compiler interleaves)
            #pragma unroll
            for (int u = 0; u < 2; ++u) if (u < nt) {
                const int ti = 2 * p + u;
                // pack UNNORMALIZED ctx; 1/l applied after the MFMA (linearity)
                half4v cf;
                #pragma unroll
                for (int j = 0; j < 4; ++j) cf[j] = (_Float16)(Oa[u][j] + Ob[u][j]);
                float4v AO = __builtin_amdgcn_mfma_f32_16x16x16f16(woF, cf, zero4, 0, 0, 0);
                const float inv = __builtin_amdgcn_rcpf(l[u]);
                float h2[4];
                #pragma unroll
                for (int j = 0; j < 4; ++j)
                    h2[j] = (float)hf[ti][j] + AO[j] * inv + (float)boH[j];
                // LN1: parallel sum + sumsq
                float s1 = (h2[0] + h2[1]) + (h2[2] + h2[3]);
                float q1 = (h2[0]*h2[0] + h2[1]*h2[1]) + (h2[2]*h2[2] + h2[3]*h2[3]);
                s1 += __shfl_xor(s1, 16); q1 += __shfl_xor(q1, 16);
                s1 += __shfl_xor(s1, 32); q1 += __shfl_xor(q1, 32);
                const float mean = s1 * 0.0625f;
                const float rstd = __builtin_amdgcn_rsqf(
                    q1 * 0.0625f - mean * mean + 1e-5f);
                #pragma unroll
                for (int j = 0; j < 4; ++j)
                    h2[j] = (h2[j] - mean) * rstd * (float)g1H[j] + (float)b1H[j];
                float fa = h2[0] * (float)w1H[0] + h2[1] * (float)w1H[1]
                         + h2[2] * (float)w1H[2] + h2[3] * (float)w1H[3];
                fa += __shfl_xor(fa, 16); fa += __shfl_xor(fa, 32);
                const float ffa = fmaxf(fa + b1v, 0.f);
                #pragma unroll
                for (int j = 0; j < 4; ++j)
                    h2[j] += ffa * (float)w2H[j] + (float)bb2H[j];
                // LN2: parallel sum + sumsq
                float s2 = (h2[0] + h2[1]) + (h2[2] + h2[3]);
                float q2 = (h2[0]*h2[0] + h2[1]*h2[1]) + (h2[2]*h2[2] + h2[3]*h2[3]);
                s2 += __shfl_xor(s2, 16); q2 += __shfl_xor(q2, 16);
                s2 += __shfl_xor(s2, 32); q2 += __shfl_xor(q2, 32);
                const float mean2 = s2 * 0.0625f;
                const float rstd2 = __builtin_amdgcn_rsqf(
                    q2 * 0.0625f - mean2 * mean2 + 1e-5f);
                if (ti < 8 || c < 2) {          // tile 8: only rows 128,129
                    #pragma unroll
                    for (int j = 0; j < 4; ++j)
                        accm[j] += (h2[j] - mean2) * rstd2 * (float)g2H[j] + (float)b2H[j];
                }
            }
        }

        // ---- mean over rows: reduce across the 16 c-lanes; store from c==0 ----
        #pragma unroll
        for (int off = 1; off < 16; off <<= 1) {
            #pragma unroll
            for (int j = 0; j < 4; ++j) accm[j] += __shfl_xor(accm[j], off);
        }
        if (c == 0) {
            float* op = &out[(size_t)batch * 16 + 4 * g];
            #pragma unroll
            for (int j = 0; j < 4; ++j) op[j] = accm[j] * (1.0f / 130.0f);
        }
    }
}

extern "C" void kernel_launch(void* const* d_in, const int* in_sizes, int n_in,
                              void* d_out, int out_size, void* d_ws, size_t ws_size,
                              hipStream_t stream) {
    const float* x      = (const float*)d_in[0];
    const float* w_proj = (const float*)d_in[1];
    const float* b_proj = (const float*)d_in[2];
    const float* w_in   = (const float*)d_in[3];
    const float* b_in   = (const float*)d_in[4];
    const float* w_out  = (const float*)d_in[5];
    const float* b_out  = (const float*)d_in[6];
    const float* ln1_g  = (const float*)d_in[7];
    const float* ln1_b  = (const float*)d_in[8];
    const float* w1     = (const float*)d_in[9];
    const float* b1     = (const float*)d_in[10];
    const float* w2     = (const float*)d_in[11];
    const float* b2     = (const float*)d_in[12];
    const float* ln2_g  = (const float*)d_in[13];
    const float* ln2_b  = (const float*)d_in[14];

    float* pe2 = (float*)d_ws;
    pe_kernel<<<9, 256, 0, stream>>>(b_proj, pe2);

    int B = in_sizes[0] / LIN;
    int grid = (B + WPB * NB - 1) / (WPB * NB);
    st_kernel<<<grid, 256, 0, stream>>>(x, w_proj, w_in, b_in,
                                        w_out, b_out, ln1_g, ln1_b,
                                        w1, b1, w2, b2, ln2_g, ln2_b,
                                        pe2, B, (float*)d_out);
}

// Round 24
// 74.993 us; speedup vs baseline: 1.6799x; 1.6799x over previous
//
#include <hip/hip_runtime.h>
#include <math.h>

#define SEQ 130
#define EMB 16
#define LIN 1039
#define NB 2          // batches per wave
#define WPB 4         // waves per block (256 threads)

typedef __attribute__((ext_vector_type(4))) _Float16 half4v;
typedef __attribute__((ext_vector_type(4))) float float4v;

// pe2[s][e] = posenc(s,e) + b_proj[e] for s<SEQ; 0 for s in [SEQ,144)
__global__ void pe_kernel(const float* __restrict__ b_proj, float* __restrict__ pe2) {
    int idx = blockIdx.x * 256 + threadIdx.x;   // s*16+e
    if (idx < 144 * 16) {
        int s = idx >> 4, e = idx & 15;
        float v = 0.f;
        if (s < SEQ) {
            int i = e >> 1;
            float div = expf(-(float)(2 * i) * 0.57564627324851149f); // ln(1e4)/16
            float ang = (float)s * div;
            v = ((e & 1) ? cosf(ang) : sinf(ang)) + b_proj[e];
        }
        pe2[idx] = v;
    }
}

// One wave = one batch end-to-end. No LDS, no barriers, no-max softmax.
// Phase 3: paired q-tiles (2-way ILP); epilogue: parallel sum/sumsq LN,
// deferred 1/l, raw v_rcp/v_rsq.
// frag(c,g,j) = M[c][4g+j]; D = mfma(M1,M2) => D[c][f] = sum_k M1[f][k]*M2[c][k]
// NOTE: no min-waves hint — R10/R13: capping VGPR below the live set causes a
// scratch-spill storm. VGPR must stay <=128 (R19: exactly 128 -> 4 waves/SIMD).
// R21/R22/R23: ANY body edit re-rolled regalloc to 144-164 -> 11% occ, regress.
// This is the exact R20 source (124 VGPR, 75.5 us) — do not perturb.
__global__ __launch_bounds__(256) void st_kernel(
    const float* __restrict__ x,
    const float* __restrict__ w_proj,
    const float* __restrict__ w_in,  const float* __restrict__ b_in,
    const float* __restrict__ w_out, const float* __restrict__ b_out,
    const float* __restrict__ ln1_g, const float* __restrict__ ln1_b,
    const float* __restrict__ w1,    const float* __restrict__ b1,
    const float* __restrict__ w2,    const float* __restrict__ b2,
    const float* __restrict__ ln2_g, const float* __restrict__ ln2_b,
    const float* __restrict__ pe2,
    int nbat,
    float* __restrict__ out)
{
    const int tid  = threadIdx.x;
    const int lane = tid & 63;
    const int c    = lane & 15;
    const int g    = lane >> 4;
    const int wgid = blockIdx.x * WPB + (tid >> 6);
    const float4v zero4 = {0.f, 0.f, 0.f, 0.f};

    // ---- per-lane weight fragments ----
    half4v wprojF, wqF, wkF, wvF, woF;
    {
        #pragma unroll
        for (int j = 0; j < 4; ++j)
            wprojF[j] = (_Float16)((g < 2) ? w_proj[c * 8 + 4 * g + j] : 0.f);
        const float* pq = &w_in[c * 16 + 4 * g];
        const float* pk = &w_in[(16 + c) * 16 + 4 * g];
        const float* pv = &w_in[(32 + c) * 16 + 4 * g];
        const float* po = &w_out[c * 16 + 4 * g];
        #pragma unroll
        for (int j = 0; j < 4; ++j) {
            wqF[j] = (_Float16)(pq[j] * 0.25f);
            wkF[j] = (_Float16)pk[j];
            wvF[j] = (_Float16)pv[j];
            woF[j] = (_Float16)po[j];
        }
    }
    // ---- packed f16 per-lane params ----
    half4v bqH, bkH, boH, g1H, b1H, g2H, b2H, w1H, w2H, bb2H;
    #pragma unroll
    for (int j = 0; j < 4; ++j) {
        const int f = 4 * g + j;
        bqH[j]  = (_Float16)(b_in[f] * 0.25f);
        bkH[j]  = (_Float16)b_in[16 + f];
        boH[j]  = (_Float16)b_out[f];
        g1H[j]  = (_Float16)ln1_g[f];  b1H[j]  = (_Float16)ln1_b[f];
        g2H[j]  = (_Float16)ln2_g[f];  b2H[j]  = (_Float16)ln2_b[f];
        w1H[j]  = (_Float16)w1[f];     w2H[j]  = (_Float16)w2[f];
        bb2H[j] = (_Float16)b2[f];
    }
    const float bvc = b_in[32 + c];
    const float b1v = b1[0];

    for (int bi = 0; bi < NB; ++bi) {
        const int batch = wgid * NB + bi;
        if (batch >= nbat) break;
        const float* xrow = x + (size_t)batch * LIN;

        // ---- phase 1: h tiles via MFMA (K padded 8->16 with zeros) ----
        half4v hf[9];
        #pragma unroll
        for (int st = 0; st < 9; ++st) {
            const int s = st * 16 + c;
            half4v xf;
            if (st < 8) {
                if (g < 2) {
                    const float* xp = &xrow[s * 8 + 4 * g];
                    #pragma unroll
                    for (int j = 0; j < 4; ++j) xf[j] = (_Float16)xp[j];
                } else {
                    #pragma unroll
                    for (int j = 0; j < 4; ++j) xf[j] = (_Float16)0.f;
                }
            } else {
                #pragma unroll
                for (int j = 0; j < 4; ++j) {
                    const int idx = s * 8 + 4 * g + j;
                    const float v = (g < 2 && idx < LIN) ? xrow[idx] : 0.f;
                    xf[j] = (_Float16)v;
                }
            }
            float4v d = __builtin_amdgcn_mfma_f32_16x16x16f16(wprojF, xf, zero4, 0, 0, 0);
            const float* pp = &pe2[s * 16 + 4 * g];
            #pragma unroll
            for (int j = 0; j < 4; ++j) hf[st][j] = (_Float16)(d[j] + pp[j]);
        }

        // ---- phase 2: k (in-lane), V^T (operand swap) ----
        half4v kf[9], vf[9];
        #pragma unroll
        for (int st = 0; st < 9; ++st) {
            float4v dk = __builtin_amdgcn_mfma_f32_16x16x16f16(wkF, hf[st], zero4, 0, 0, 0);
            float4v dv = __builtin_amdgcn_mfma_f32_16x16x16f16(hf[st], wvF, zero4, 0, 0, 0);
            #pragma unroll
            for (int j = 0; j < 4; ++j) {
                kf[st][j] = (_Float16)(dk[j] + (float)bkH[j]);
                vf[st][j] = (_Float16)(dv[j] + bvc);
            }
        }

        // ---- phase 3: paired tiles — 2 independent chains everywhere ----
        float accm[4] = {0.f, 0.f, 0.f, 0.f};
        #pragma unroll
        for (int p = 0; p < 5; ++p) {
            const int nt = (p < 4) ? 2 : 1;     // pair (0..3), tile 8 alone
            half4v qf[2];
            float4v Oa[2], Ob[2];
            float l[2];
            #pragma unroll
            for (int u = 0; u < 2; ++u) if (u < nt) {
                const int ti = 2 * p + u;
                float4v dq = __builtin_amdgcn_mfma_f32_16x16x16f16(wqF, hf[ti], zero4, 0, 0, 0);
                #pragma unroll
                for (int j = 0; j < 4; ++j) qf[u][j] = (_Float16)(dq[j] + (float)bqH[j]);
                Oa[u] = zero4; Ob[u] = zero4; l[u] = 0.f;
            }
            #pragma unroll
            for (int kt = 0; kt < 9; ++kt) {
                #pragma unroll
                for (int u = 0; u < 2; ++u) if (u < nt) {
                    float4v s4 = __builtin_amdgcn_mfma_f32_16x16x16f16(kf[kt], qf[u], zero4, 0, 0, 0);
                    float p0 = __expf(s4[0]), p1 = __expf(s4[1]);
                    float p2 = __expf(s4[2]), p3 = __expf(s4[3]);
                    if (kt == 8) {      // k-rows 128+4g+j valid only when 4g+j<2
                        p2 = 0.f; p3 = 0.f;
                        if (g > 0) { p0 = 0.f; p1 = 0.f; }
                    }
                    l[u] += (p0 + p1) + (p2 + p3);
                    half4v pf = {(_Float16)p0, (_Float16)p1, (_Float16)p2, (_Float16)p3};
                    if (kt & 1) Ob[u] = __builtin_amdgcn_mfma_f32_16x16x16f16(vf[kt], pf, Ob[u], 0, 0, 0);
                    else        Oa[u] = __builtin_amdgcn_mfma_f32_16x16x16f16(vf[kt], pf, Oa[u], 0, 0, 0);
                }
            }
            #pragma unroll
            for (int u = 0; u < 2; ++u) if (u < nt) l[u] += __shfl_xor(l[u], 16);
            #pragma unroll
            for (int u = 0; u < 2; ++u) if (u < nt) l[u] += __shfl_xor(l[u], 32);
            // two independent epilogues (compiler interleaves)
            #pragma unroll
            for (int u = 0; u < 2; ++u) if (u < nt) {
                const int ti = 2 * p + u;
                // pack UNNORMALIZED ctx; 1/l applied after the MFMA (linearity)
                half4v cf;
                #pragma unroll
                for (int j = 0; j < 4; ++j) cf[j] = (_Float16)(Oa[u][j] + Ob[u][j]);
                float4v AO = __builtin_amdgcn_mfma_f32_16x16x16f16(woF, cf, zero4, 0, 0, 0);
                const float inv = __builtin_amdgcn_rcpf(l[u]);
                float h2[4];
                #pragma unroll
                for (int j = 0; j < 4; ++j)
                    h2[j] = (float)hf[ti][j] + AO[j] * inv + (float)boH[j];
                // LN1: parallel sum + sumsq
                float s1 = (h2[0] + h2[1]) + (h2[2] + h2[3]);
                float q1 = (h2[0]*h2[0] + h2[1]*h2[1]) + (h2[2]*h2[2] + h2[3]*h2[3]);
                s1 += __shfl_xor(s1, 16); q1 += __shfl_xor(q1, 16);
                s1 += __shfl_xor(s1, 32); q1 += __shfl_xor(q1, 32);
                const float mean = s1 * 0.0625f;
                const float rstd = __builtin_amdgcn_rsqf(
                    q1 * 0.0625f - mean * mean + 1e-5f);
                #pragma unroll
                for (int j = 0; j < 4; ++j)
                    h2[j] = (h2[j] - mean) * rstd * (float)g1H[j] + (float)b1H[j];
                float fa = h2[0] * (float)w1H[0] + h2[1] * (float)w1H[1]
                         + h2[2] * (float)w1H[2] + h2[3] * (float)w1H[3];
                fa += __shfl_xor(fa, 16); fa += __shfl_xor(fa, 32);
                const float ffa = fmaxf(fa + b1v, 0.f);
                #pragma unroll
                for (int j = 0; j < 4; ++j)
                    h2[j] += ffa * (float)w2H[j] + (float)bb2H[j];
                // LN2: parallel sum + sumsq
                float s2 = (h2[0] + h2[1]) + (h2[2] + h2[3]);
                float q2 = (h2[0]*h2[0] + h2[1]*h2[1]) + (h2[2]*h2[2] + h2[3]*h2[3]);
                s2 += __shfl_xor(s2, 16); q2 += __shfl_xor(q2, 16);
                s2 += __shfl_xor(s2, 32); q2 += __shfl_xor(q2, 32);
                const float mean2 = s2 * 0.0625f;
                const float rstd2 = __builtin_amdgcn_rsqf(
                    q2 * 0.0625f - mean2 * mean2 + 1e-5f);
                if (ti < 8 || c < 2) {          // tile 8: only rows 128,129
                    #pragma unroll
                    for (int j = 0; j < 4; ++j)
                        accm[j] += (h2[j] - mean2) * rstd2 * (float)g2H[j] + (float)b2H[j];
                }
            }
        }

        // ---- mean over rows: reduce across the 16 c-lanes; store from c==0 ----
        #pragma unroll
        for (int off = 1; off < 16; off <<= 1) {
            #pragma unroll
            for (int j = 0; j < 4; ++j) accm[j] += __shfl_xor(accm[j], off);
        }
        if (c == 0) {
            float* op = &out[(size_t)batch * 16 + 4 * g];
            #pragma unroll
            for (int j = 0; j < 4; ++j) op[j] = accm[j] * (1.0f / 130.0f);
        }
    }
}

extern "C" void kernel_launch(void* const* d_in, const int* in_sizes, int n_in,
                              void* d_out, int out_size, void* d_ws, size_t ws_size,
                              hipStream_t stream) {
    const float* x      = (const float*)d_in[0];
    const float* w_proj = (const float*)d_in[1];
    const float* b_proj = (const float*)d_in[2];
    const float* w_in   = (const float*)d_in[3];
    const float* b_in   = (const float*)d_in[4];
    const float* w_out  = (const float*)d_in[5];
    const float* b_out  = (const float*)d_in[6];
    const float* ln1_g  = (const float*)d_in[7];
    const float* ln1_b  = (const float*)d_in[8];
    const float* w1     = (const float*)d_in[9];
    const float* b1     = (const float*)d_in[10];
    const float* w2     = (const float*)d_in[11];
    const float* b2     = (const float*)d_in[12];
    const float* ln2_g  = (const float*)d_in[13];
    const float* ln2_b  = (const float*)d_in[14];

    float* pe2 = (float*)d_ws;
    pe_kernel<<<9, 256, 0, stream>>>(b_proj, pe2);

    int B = in_sizes[0] / LIN;
    int grid = (B + WPB * NB - 1) / (WPB * NB);
    st_kernel<<<grid, 256, 0, stream>>>(x, w_proj, w_in, b_in,
                                        w_out, b_out, ln1_g, ln1_b,
                                        w1, b1, w2, b2, ln2_g, ln2_b,
                                        pe2, B, (float*)d_out);
}

// Round 25
// 74.807 us; speedup vs baseline: 1.6840x; 1.0025x over previous
//
#include <hip/hip_runtime.h>
#include <math.h>

#define SEQ 130
#define EMB 16
#define LIN 1039
#define NB 2          // batches per wave
#define WPB 4         // waves per block (256 threads)

typedef __attribute__((ext_vector_type(4))) _Float16 half4v;
typedef __attribute__((ext_vector_type(4))) float float4v;

// pe2[s][e] = posenc(s,e) + b_proj[e] for s<SEQ; 0 for s in [SEQ,144)
__global__ void pe_kernel(const float* __restrict__ b_proj, float* __restrict__ pe2) {
    int idx = blockIdx.x * 256 + threadIdx.x;   // s*16+e
    if (idx < 144 * 16) {
        int s = idx >> 4, e = idx & 15;
        float v = 0.f;
        if (s < SEQ) {
            int i = e >> 1;
            float div = expf(-(float)(2 * i) * 0.57564627324851149f); // ln(1e4)/16
            float ang = (float)s * div;
            v = ((e & 1) ? cosf(ang) : sinf(ang)) + b_proj[e];
        }
        pe2[idx] = v;
    }
}

// One wave = one batch end-to-end. No LDS, no barriers, no-max softmax.
// Phase 3: paired q-tiles (2-way ILP); epilogue: parallel sum/sumsq LN,
// deferred 1/l, raw v_rcp/v_rsq. R25: s_setprio(1) around the MFMA-dense
// inner loop (liveness-neutral; waves are independent -> T5-positive case).
// frag(c,g,j) = M[c][4g+j]; D = mfma(M1,M2) => D[c][f] = sum_k M1[f][k]*M2[c][k]
// NOTE: no min-waves hint — R10/R13: capping VGPR below the live set causes a
// scratch-spill storm. VGPR must stay <=128 (R19: exactly 128 -> 4 waves/SIMD).
// R21/R22/R23: ANY liveness edit re-rolled regalloc to 144-164 -> 11% occ.
__global__ __launch_bounds__(256) void st_kernel(
    const float* __restrict__ x,
    const float* __restrict__ w_proj,
    const float* __restrict__ w_in,  const float* __restrict__ b_in,
    const float* __restrict__ w_out, const float* __restrict__ b_out,
    const float* __restrict__ ln1_g, const float* __restrict__ ln1_b,
    const float* __restrict__ w1,    const float* __restrict__ b1,
    const float* __restrict__ w2,    const float* __restrict__ b2,
    const float* __restrict__ ln2_g, const float* __restrict__ ln2_b,
    const float* __restrict__ pe2,
    int nbat,
    float* __restrict__ out)
{
    const int tid  = threadIdx.x;
    const int lane = tid & 63;
    const int c    = lane & 15;
    const int g    = lane >> 4;
    const int wgid = blockIdx.x * WPB + (tid >> 6);
    const float4v zero4 = {0.f, 0.f, 0.f, 0.f};

    // ---- per-lane weight fragments ----
    half4v wprojF, wqF, wkF, wvF, woF;
    {
        #pragma unroll
        for (int j = 0; j < 4; ++j)
            wprojF[j] = (_Float16)((g < 2) ? w_proj[c * 8 + 4 * g + j] : 0.f);
        const float* pq = &w_in[c * 16 + 4 * g];
        const float* pk = &w_in[(16 + c) * 16 + 4 * g];
        const float* pv = &w_in[(32 + c) * 16 + 4 * g];
        const float* po = &w_out[c * 16 + 4 * g];
        #pragma unroll
        for (int j = 0; j < 4; ++j) {
            wqF[j] = (_Float16)(pq[j] * 0.25f);
            wkF[j] = (_Float16)pk[j];
            wvF[j] = (_Float16)pv[j];
            woF[j] = (_Float16)po[j];
        }
    }
    // ---- packed f16 per-lane params ----
    half4v bqH, bkH, boH, g1H, b1H, g2H, b2H, w1H, w2H, bb2H;
    #pragma unroll
    for (int j = 0; j < 4; ++j) {
        const int f = 4 * g + j;
        bqH[j]  = (_Float16)(b_in[f] * 0.25f);
        bkH[j]  = (_Float16)b_in[16 + f];
        boH[j]  = (_Float16)b_out[f];
        g1H[j]  = (_Float16)ln1_g[f];  b1H[j]  = (_Float16)ln1_b[f];
        g2H[j]  = (_Float16)ln2_g[f];  b2H[j]  = (_Float16)ln2_b[f];
        w1H[j]  = (_Float16)w1[f];     w2H[j]  = (_Float16)w2[f];
        bb2H[j] = (_Float16)b2[f];
    }
    const float bvc = b_in[32 + c];
    const float b1v = b1[0];

    for (int bi = 0; bi < NB; ++bi) {
        const int batch = wgid * NB + bi;
        if (batch >= nbat) break;
        const float* xrow = x + (size_t)batch * LIN;

        // ---- phase 1: h tiles via MFMA (K padded 8->16 with zeros) ----
        half4v hf[9];
        #pragma unroll
        for (int st = 0; st < 9; ++st) {
            const int s = st * 16 + c;
            half4v xf;
            if (st < 8) {
                if (g < 2) {
                    const float* xp = &xrow[s * 8 + 4 * g];
                    #pragma unroll
                    for (int j = 0; j < 4; ++j) xf[j] = (_Float16)xp[j];
                } else {
                    #pragma unroll
                    for (int j = 0; j < 4; ++j) xf[j] = (_Float16)0.f;
                }
            } else {
                #pragma unroll
                for (int j = 0; j < 4; ++j) {
                    const int idx = s * 8 + 4 * g + j;
                    const float v = (g < 2 && idx < LIN) ? xrow[idx] : 0.f;
                    xf[j] = (_Float16)v;
                }
            }
            float4v d = __builtin_amdgcn_mfma_f32_16x16x16f16(wprojF, xf, zero4, 0, 0, 0);
            const float* pp = &pe2[s * 16 + 4 * g];
            #pragma unroll
            for (int j = 0; j < 4; ++j) hf[st][j] = (_Float16)(d[j] + pp[j]);
        }

        // ---- phase 2: k (in-lane), V^T (operand swap) ----
        half4v kf[9], vf[9];
        #pragma unroll
        for (int st = 0; st < 9; ++st) {
            float4v dk = __builtin_amdgcn_mfma_f32_16x16x16f16(wkF, hf[st], zero4, 0, 0, 0);
            float4v dv = __builtin_amdgcn_mfma_f32_16x16x16f16(hf[st], wvF, zero4, 0, 0, 0);
            #pragma unroll
            for (int j = 0; j < 4; ++j) {
                kf[st][j] = (_Float16)(dk[j] + (float)bkH[j]);
                vf[st][j] = (_Float16)(dv[j] + bvc);
            }
        }

        // ---- phase 3: paired tiles — 2 independent chains everywhere ----
        float accm[4] = {0.f, 0.f, 0.f, 0.f};
        #pragma unroll
        for (int p = 0; p < 5; ++p) {
            const int nt = (p < 4) ? 2 : 1;     // pair (0..3), tile 8 alone
            half4v qf[2];
            float4v Oa[2], Ob[2];
            float l[2];
            #pragma unroll
            for (int u = 0; u < 2; ++u) if (u < nt) {
                const int ti = 2 * p + u;
                float4v dq = __builtin_amdgcn_mfma_f32_16x16x16f16(wqF, hf[ti], zero4, 0, 0, 0);
                #pragma unroll
                for (int j = 0; j < 4; ++j) qf[u][j] = (_Float16)(dq[j] + (float)bqH[j]);
                Oa[u] = zero4; Ob[u] = zero4; l[u] = 0.f;
            }
            // MFMA-dense region: bias the CU scheduler toward this wave
            __builtin_amdgcn_s_setprio(1);
            #pragma unroll
            for (int kt = 0; kt < 9; ++kt) {
                #pragma unroll
                for (int u = 0; u < 2; ++u) if (u < nt) {
                    float4v s4 = __builtin_amdgcn_mfma_f32_16x16x16f16(kf[kt], qf[u], zero4, 0, 0, 0);
                    float p0 = __expf(s4[0]), p1 = __expf(s4[1]);
                    float p2 = __expf(s4[2]), p3 = __expf(s4[3]);
                    if (kt == 8) {      // k-rows 128+4g+j valid only when 4g+j<2
                        p2 = 0.f; p3 = 0.f;
                        if (g > 0) { p0 = 0.f; p1 = 0.f; }
                    }
                    l[u] += (p0 + p1) + (p2 + p3);
                    half4v pf = {(_Float16)p0, (_Float16)p1, (_Float16)p2, (_Float16)p3};
                    if (kt & 1) Ob[u] = __builtin_amdgcn_mfma_f32_16x16x16f16(vf[kt], pf, Ob[u], 0, 0, 0);
                    else        Oa[u] = __builtin_amdgcn_mfma_f32_16x16x16f16(vf[kt], pf, Oa[u], 0, 0, 0);
                }
            }
            __builtin_amdgcn_s_setprio(0);
            #pragma unroll
            for (int u = 0; u < 2; ++u) if (u < nt) l[u] += __shfl_xor(l[u], 16);
            #pragma unroll
            for (int u = 0; u < 2; ++u) if (u < nt) l[u] += __shfl_xor(l[u], 32);
            // two independent epilogues (compiler interleaves)
            #pragma unroll
            for (int u = 0; u < 2; ++u) if (u < nt) {
                const int ti = 2 * p + u;
                // pack UNNORMALIZED ctx; 1/l applied after the MFMA (linearity)
                half4v cf;
                #pragma unroll
                for (int j = 0; j < 4; ++j) cf[j] = (_Float16)(Oa[u][j] + Ob[u][j]);
                float4v AO = __builtin_amdgcn_mfma_f32_16x16x16f16(woF, cf, zero4, 0, 0, 0);
                const float inv = __builtin_amdgcn_rcpf(l[u]);
                float h2[4];
                #pragma unroll
                for (int j = 0; j < 4; ++j)
                    h2[j] = (float)hf[ti][j] + AO[j] * inv + (float)boH[j];
                // LN1: parallel sum + sumsq
                float s1 = (h2[0] + h2[1]) + (h2[2] + h2[3]);
                float q1 = (h2[0]*h2[0] + h2[1]*h2[1]) + (h2[2]*h2[2] + h2[3]*h2[3]);
                s1 += __shfl_xor(s1, 16); q1 += __shfl_xor(q1, 16);
                s1 += __shfl_xor(s1, 32); q1 += __shfl_xor(q1, 32);
                const float mean = s1 * 0.0625f;
                const float rstd = __builtin_amdgcn_rsqf(
                    q1 * 0.0625f - mean * mean + 1e-5f);
                #pragma unroll
                for (int j = 0; j < 4; ++j)
                    h2[j] = (h2[j] - mean) * rstd * (float)g1H[j] + (float)b1H[j];
                float fa = h2[0] * (float)w1H[0] + h2[1] * (float)w1H[1]
                         + h2[2] * (float)w1H[2] + h2[3] * (float)w1H[3];
                fa += __shfl_xor(fa, 16); fa += __shfl_xor(fa, 32);
                const float ffa = fmaxf(fa + b1v, 0.f);
                #pragma unroll
                for (int j = 0; j < 4; ++j)
                    h2[j] += ffa * (float)w2H[j] + (float)bb2H[j];
                // LN2: parallel sum + sumsq
                float s2 = (h2[0] + h2[1]) + (h2[2] + h2[3]);
                float q2 = (h2[0]*h2[0] + h2[1]*h2[1]) + (h2[2]*h2[2] + h2[3]*h2[3]);
                s2 += __shfl_xor(s2, 16); q2 += __shfl_xor(q2, 16);
                s2 += __shfl_xor(s2, 32); q2 += __shfl_xor(q2, 32);
                const float mean2 = s2 * 0.0625f;
                const float rstd2 = __builtin_amdgcn_rsqf(
                    q2 * 0.0625f - mean2 * mean2 + 1e-5f);
                if (ti < 8 || c < 2) {          // tile 8: only rows 128,129
                    #pragma unroll
                    for (int j = 0; j < 4; ++j)
                        accm[j] += (h2[j] - mean2) * rstd2 * (float)g2H[j] + (float)b2H[j];
                }
            }
        }

        // ---- mean over rows: reduce across the 16 c-lanes; store from c==0 ----
        #pragma unroll
        for (int off = 1; off < 16; off <<= 1) {
            #pragma unroll
            for (int j = 0; j < 4; ++j) accm[j] += __shfl_xor(accm[j], off);
        }
        if (c == 0) {
            float* op = &out[(size_t)batch * 16 + 4 * g];
            #pragma unroll
            for (int j = 0; j < 4; ++j) op[j] = accm[j] * (1.0f / 130.0f);
        }
    }
}

extern "C" void kernel_launch(void* const* d_in, const int* in_sizes, int n_in,
                              void* d_out, int out_size, void* d_ws, size_t ws_size,
                              hipStream_t stream) {
    const float* x      = (const float*)d_in[0];
    const float* w_proj = (const float*)d_in[1];
    const float* b_proj = (const float*)d_in[2];
    const float* w_in   = (const float*)d_in[3];
    const float* b_in   = (const float*)d_in[4];
    const float* w_out  = (const float*)d_in[5];
    const float* b_out  = (const float*)d_in[6];
    const float* ln1_g  = (const float*)d_in[7];
    const float* ln1_b  = (const float*)d_in[8];
    const float* w1     = (const float*)d_in[9];
    const float* b1     = (const float*)d_in[10];
    const float* w2     = (const float*)d_in[11];
    const float* b2     = (const float*)d_in[12];
    const float* ln2_g  = (const float*)d_in[13];
    const float* ln2_b  = (const float*)d_in[14];

    float* pe2 = (float*)d_ws;
    pe_kernel<<<9, 256, 0, stream>>>(b_proj, pe2);

    int B = in_sizes[0] / LIN;
    int grid = (B + WPB * NB - 1) / (WPB * NB);
    st_kernel<<<grid, 256, 0, stream>>>(x, w_proj, w_in, b_in,
                                        w_out, b_out, ln1_g, ln1_b,
                                        w1, b1, w2, b2, ln2_g, ln2_b,
                                        pe2, B, (float*)d_out);
}